// Round 15
// baseline (26.510 us; speedup 1.0000x reference)
//
#include <hip/hip_runtime.h>

// BiorUpSampling: 2x zero-interleaved upsample + separable symmetric 9-tap
// filter, SAME zero padding. Polyphase, register-streaming 5-row ring,
// 2-deep load prefetch (R10 structure). Cache-policy A/B, last untested cell:
// NT LOADS (input bypasses L2 — it is read ~once and the harness poison
// evicts it between replays anyway) + PLAIN stores (output streams through
// L2 writeback, the path the 6.6 TB/s fill kernel uses). Theory: R8's
// plain-store regression was input/output L2 contention, not the store path.

constexpr int H = 512, W = 512;
constexpr int RP = 8;   // input rows advanced per block -> 16 output rows

typedef float f32x4 __attribute__((ext_vector_type(4)));
typedef float f32x2 __attribute__((ext_vector_type(2)));

__global__ __launch_bounds__(256)
void bior_up_kernel(const float* __restrict__ in, float* __restrict__ out) {
  constexpr float E0 =  0.03782845550699535f;
  constexpr float E1 = -0.1106244044184226f;
  constexpr float E2 =  0.8526986790094022f;
  constexpr float E3 = -0.1106244044184226f;
  constexpr float E4 =  0.03782845550699535f;
  constexpr float O0 = -0.02384946501937986f;
  constexpr float O1 =  0.3774028556126536f;
  constexpr float O2 =  0.3774028556126537f;
  constexpr float O3 = -0.02384946501937986f;

  const int tid = threadIdx.x;
  const int r0  = blockIdx.x * RP;
  const int b   = blockIdx.y;
  const float* inb  = in  + (size_t)b * H * W;
  float*       outb = out + (size_t)b * (2 * H) * (2 * W);

  const int c = 2 * tid;              // this thread's input cols: c, c+1
  const bool lv = (c >= 2);
  const bool rv = (c <= W - 4);

  auto loadrow = [&](int gr, f32x2& L, f32x2& M, f32x2& R) {
    const bool rowv = ((unsigned)gr < (unsigned)H);
    const float* rowp = inb + (size_t)gr * W;
    const f32x2 z = {0.0f, 0.0f};
    L = (rowv && lv) ? __builtin_nontemporal_load(reinterpret_cast<const f32x2*>(rowp + c - 2)) : z;
    M =  rowv        ? __builtin_nontemporal_load(reinterpret_cast<const f32x2*>(rowp + c))     : z;
    R = (rowv && rv) ? __builtin_nontemporal_load(reinterpret_cast<const f32x2*>(rowp + c + 2)) : z;
  };
  auto hfilt = [&](f32x2 L, f32x2 M, f32x2 R,
                   float& a, float& bb, float& cc, float& dd) {
    const float v0 = L.x, v1 = L.y, v2 = M.x, v3 = M.y, v4 = R.x, v5 = R.y;
    a  = v0*E0 + v1*E1 + v2*E2 + v3*E3 + v4*E4;   // he(c)   -> out col 2c
    bb = v1*O0 + v2*O1 + v3*O2 + v4*O3;           // ho(c)   -> out col 2c+1
    cc = v1*E0 + v2*E1 + v3*E2 + v4*E3 + v5*E4;   // he(c+1) -> out col 2c+2
    dd = v2*O0 + v3*O1 + v4*O2 + v5*O3;           // ho(c+1) -> out col 2c+3
  };

  // Ring of horizontally-filtered rows; slot k holds row (center-2+k).
  float A[5], B[5], C[5], D[5];

  // Prologue: issue all 6 lead-in row loads back-to-back, then compute.
  f32x2 La, Ma, Ra, Lb, Mb, Rb, Lc, Mc, Rc, Ld, Md, Rd;
  f32x2 L0, M0, R0, L1, M1, R1, L2, M2, R2;
  loadrow(r0 - 2, La, Ma, Ra);
  loadrow(r0 - 1, Lb, Mb, Rb);
  loadrow(r0    , Lc, Mc, Rc);
  loadrow(r0 + 1, Ld, Md, Rd);
  loadrow(r0 + 2, L0, M0, R0);   // consumed at p=0
  loadrow(r0 + 3, L1, M1, R1);   // consumed at p=1
  hfilt(La, Ma, Ra, A[0], B[0], C[0], D[0]);
  hfilt(Lb, Mb, Rb, A[1], B[1], C[1], D[1]);
  hfilt(Lc, Mc, Rc, A[2], B[2], C[2], D[2]);
  hfilt(Ld, Md, Rd, A[3], B[3], C[3], D[3]);

#pragma unroll
  for (int p = 0; p < RP; ++p) {
    if (p + 2 < RP) loadrow(r0 + 4 + p, L2, M2, R2);   // 2-deep prefetch

    hfilt(L0, M0, R0, A[4], B[4], C[4], D[4]);         // consume oldest set

    f32x4 ev, od;
    ev.x = A[0]*E0 + A[1]*E1 + A[2]*E2 + A[3]*E3 + A[4]*E4;
    ev.y = B[0]*E0 + B[1]*E1 + B[2]*E2 + B[3]*E3 + B[4]*E4;
    ev.z = C[0]*E0 + C[1]*E1 + C[2]*E2 + C[3]*E3 + C[4]*E4;
    ev.w = D[0]*E0 + D[1]*E1 + D[2]*E2 + D[3]*E3 + D[4]*E4;
    od.x = A[1]*O0 + A[2]*O1 + A[3]*O2 + A[4]*O3;
    od.y = B[1]*O0 + B[2]*O1 + B[3]*O2 + B[4]*O3;
    od.z = C[1]*O0 + C[2]*O1 + C[3]*O2 + C[4]*O3;
    od.w = D[1]*O0 + D[2]*O1 + D[3]*O2 + D[4]*O3;

    const int row_e = 2 * (r0 + p);
    *reinterpret_cast<f32x4*>(&outb[(size_t)row_e       * (2 * W) + 4 * tid]) = ev;
    *reinterpret_cast<f32x4*>(&outb[(size_t)(row_e + 1) * (2 * W) + 4 * tid]) = od;

#pragma unroll
    for (int k = 0; k < 4; ++k) {
      A[k] = A[k + 1]; B[k] = B[k + 1]; C[k] = C[k + 1]; D[k] = D[k + 1];
    }
    L0 = L1; M0 = M1; R0 = R1;
    L1 = L2; M1 = M2; R1 = R2;
  }
}

extern "C" void kernel_launch(void* const* d_in, const int* in_sizes, int n_in,
                              void* d_out, int out_size, void* d_ws, size_t ws_size,
                              hipStream_t stream) {
  const float* in = (const float*)d_in[0];
  float* out = (float*)d_out;
  const int batch = in_sizes[0] / (H * W);
  dim3 grid(H / RP, batch);   // 64 x 16 = 1024 blocks -> 4 blocks/CU
  bior_up_kernel<<<grid, 256, 0, stream>>>(in, out);
}

// Round 16
// 18.366 us; speedup vs baseline: 1.4434x; 1.4434x over previous
//
#include <hip/hip_runtime.h>

// BiorUpSampling: 2x zero-interleaved upsample + separable symmetric 9-tap
// filter, SAME zero padding. Polyphase, register-streaming ring, NT stores.
// R16: 2 row-pairs per iteration (6-slot ring, 2-row load FIFO) -> 4 NT
// stores issued back-to-back per iteration = 2x per-wave outstanding writes,
// half the vmcnt wait points per store (loads+stores share one in-order
// counter). Grid/geometry identical to R10 (1024 blocks, 2 cols/thread).

constexpr int H = 512, W = 512;
constexpr int RP = 8;   // input rows advanced per block -> 16 output rows
constexpr int IT = RP / 2;  // 4 iterations x 2 row-pairs

typedef float f32x4 __attribute__((ext_vector_type(4)));
typedef float f32x2 __attribute__((ext_vector_type(2)));

__global__ __launch_bounds__(256, 4)
void bior_up_kernel(const float* __restrict__ in, float* __restrict__ out) {
  constexpr float E0 =  0.03782845550699535f;
  constexpr float E1 = -0.1106244044184226f;
  constexpr float E2 =  0.8526986790094022f;
  constexpr float E3 = -0.1106244044184226f;
  constexpr float E4 =  0.03782845550699535f;
  constexpr float O0 = -0.02384946501937986f;
  constexpr float O1 =  0.3774028556126536f;
  constexpr float O2 =  0.3774028556126537f;
  constexpr float O3 = -0.02384946501937986f;

  const int tid = threadIdx.x;
  const int r0  = blockIdx.x * RP;
  const int b   = blockIdx.y;
  const float* inb  = in  + (size_t)b * H * W;
  float*       outb = out + (size_t)b * (2 * H) * (2 * W);

  const int c = 2 * tid;              // this thread's input cols: c, c+1
  const bool lv = (c >= 2);
  const bool rv = (c <= W - 4);

  auto loadrow = [&](int gr, f32x2& L, f32x2& M, f32x2& R) {
    const bool rowv = ((unsigned)gr < (unsigned)H);
    const float* rowp = inb + (size_t)gr * W;
    const f32x2 z = {0.0f, 0.0f};
    L = (rowv && lv) ? *reinterpret_cast<const f32x2*>(rowp + c - 2) : z;
    M =  rowv        ? *reinterpret_cast<const f32x2*>(rowp + c)     : z;
    R = (rowv && rv) ? *reinterpret_cast<const f32x2*>(rowp + c + 2) : z;
  };
  auto hfilt = [&](f32x2 L, f32x2 M, f32x2 R,
                   float& a, float& bb, float& cc, float& dd) {
    const float v0 = L.x, v1 = L.y, v2 = M.x, v3 = M.y, v4 = R.x, v5 = R.y;
    a  = v0*E0 + v1*E1 + v2*E2 + v3*E3 + v4*E4;   // he(c)   -> out col 2c
    bb = v1*O0 + v2*O1 + v3*O2 + v4*O3;           // ho(c)   -> out col 2c+1
    cc = v1*E0 + v2*E1 + v3*E2 + v4*E3 + v5*E4;   // he(c+1) -> out col 2c+2
    dd = v2*O0 + v3*O1 + v4*O2 + v5*O3;           // ho(c+1) -> out col 2c+3
  };

  // 6-slot ring: at iter t's compute, slot k holds h-filtered row r0+2t-2+k.
  float A[6], B[6], C[6], D[6];

  // Prologue: issue 6 rows of loads back-to-back (4 ring + 2 FIFO).
  f32x2 La, Ma, Ra, Lb, Mb, Rb, Lc, Mc, Rc, Ld, Md, Rd;
  f32x2 L0, M0, R0, L1, M1, R1;   // FIFO: rows consumed THIS iteration
  f32x2 L2, M2, R2, L3, M3, R3;   // FIFO2: rows for the NEXT iteration
  loadrow(r0 - 2, La, Ma, Ra);
  loadrow(r0 - 1, Lb, Mb, Rb);
  loadrow(r0    , Lc, Mc, Rc);
  loadrow(r0 + 1, Ld, Md, Rd);
  loadrow(r0 + 2, L0, M0, R0);
  loadrow(r0 + 3, L1, M1, R1);
  hfilt(La, Ma, Ra, A[0], B[0], C[0], D[0]);
  hfilt(Lb, Mb, Rb, A[1], B[1], C[1], D[1]);
  hfilt(Lc, Mc, Rc, A[2], B[2], C[2], D[2]);
  hfilt(Ld, Md, Rd, A[3], B[3], C[3], D[3]);

#pragma unroll
  for (int t = 0; t < IT; ++t) {
    if (t + 1 < IT) {                     // prefetch next iteration's 2 rows
      loadrow(r0 + 4 + 2 * t, L2, M2, R2);
      loadrow(r0 + 5 + 2 * t, L3, M3, R3);
    }

    hfilt(L0, M0, R0, A[4], B[4], C[4], D[4]);   // rows r0+2t+2
    hfilt(L1, M1, R1, A[5], B[5], C[5], D[5]);   // rows r0+2t+3

    // Two output row-pairs; 4 NT stores issued back-to-back.
    f32x4 ev0, od0, ev1, od1;
    ev0.x = A[0]*E0 + A[1]*E1 + A[2]*E2 + A[3]*E3 + A[4]*E4;
    ev0.y = B[0]*E0 + B[1]*E1 + B[2]*E2 + B[3]*E3 + B[4]*E4;
    ev0.z = C[0]*E0 + C[1]*E1 + C[2]*E2 + C[3]*E3 + C[4]*E4;
    ev0.w = D[0]*E0 + D[1]*E1 + D[2]*E2 + D[3]*E3 + D[4]*E4;
    od0.x = A[1]*O0 + A[2]*O1 + A[3]*O2 + A[4]*O3;
    od0.y = B[1]*O0 + B[2]*O1 + B[3]*O2 + B[4]*O3;
    od0.z = C[1]*O0 + C[2]*O1 + C[3]*O2 + C[4]*O3;
    od0.w = D[1]*O0 + D[2]*O1 + D[3]*O2 + D[4]*O3;
    ev1.x = A[1]*E0 + A[2]*E1 + A[3]*E2 + A[4]*E3 + A[5]*E4;
    ev1.y = B[1]*E0 + B[2]*E1 + B[3]*E2 + B[4]*E3 + B[5]*E4;
    ev1.z = C[1]*E0 + C[2]*E1 + C[3]*E2 + C[4]*E3 + C[5]*E4;
    ev1.w = D[1]*E0 + D[2]*E1 + D[3]*E2 + D[4]*E3 + D[5]*E4;
    od1.x = A[2]*O0 + A[3]*O1 + A[4]*O2 + A[5]*O3;
    od1.y = B[2]*O0 + B[3]*O1 + B[4]*O2 + B[5]*O3;
    od1.z = C[2]*O0 + C[3]*O1 + C[4]*O2 + C[5]*O3;
    od1.w = D[2]*O0 + D[3]*O1 + D[4]*O2 + D[5]*O3;

    const int row_e = 2 * (r0 + 2 * t);
    float* base = &outb[(size_t)row_e * (2 * W) + 4 * tid];
    __builtin_nontemporal_store(ev0, reinterpret_cast<f32x4*>(base));
    __builtin_nontemporal_store(od0, reinterpret_cast<f32x4*>(base + 2 * W));
    __builtin_nontemporal_store(ev1, reinterpret_cast<f32x4*>(base + 4 * W));
    __builtin_nontemporal_store(od1, reinterpret_cast<f32x4*>(base + 6 * W));

#pragma unroll
    for (int k = 0; k < 4; ++k) {
      A[k] = A[k + 2]; B[k] = B[k + 2]; C[k] = C[k + 2]; D[k] = D[k + 2];
    }
    L0 = L2; M0 = M2; R0 = R2;
    L1 = L3; M1 = M3; R1 = R3;
  }
}

extern "C" void kernel_launch(void* const* d_in, const int* in_sizes, int n_in,
                              void* d_out, int out_size, void* d_ws, size_t ws_size,
                              hipStream_t stream) {
  const float* in = (const float*)d_in[0];
  float* out = (float*)d_out;
  const int batch = in_sizes[0] / (H * W);
  dim3 grid(H / RP, batch);   // 64 x 16 = 1024 blocks -> 4 blocks/CU
  bior_up_kernel<<<grid, 256, 0, stream>>>(in, out);
}

// Round 17
// 18.321 us; speedup vs baseline: 1.4470x; 1.0025x over previous
//
#include <hip/hip_runtime.h>

// BiorUpSampling: 2x zero-interleaved upsample + separable symmetric 9-tap
// filter, SAME zero padding. Polyphase, register-streaming ring, NT stores.
// R17: 4 row-pairs per iteration (8-slot ring, 4-row FIFO, 2 iterations) ->
// 8 NT stores issued back-to-back = 2x R16's outstanding writes per wait
// point. Store-burst ladder: 2/burst=19.0, 4/burst=18.4, this tests 8.

constexpr int H = 512, W = 512;
constexpr int RP = 8;       // input rows advanced per block -> 16 output rows
constexpr int PR = 4;       // row-pairs per iteration
constexpr int IT = RP / PR; // 2 iterations

typedef float f32x4 __attribute__((ext_vector_type(4)));
typedef float f32x2 __attribute__((ext_vector_type(2)));

__global__ __launch_bounds__(256, 4)
void bior_up_kernel(const float* __restrict__ in, float* __restrict__ out) {
  constexpr float E0 =  0.03782845550699535f;
  constexpr float E1 = -0.1106244044184226f;
  constexpr float E2 =  0.8526986790094022f;
  constexpr float E3 = -0.1106244044184226f;
  constexpr float E4 =  0.03782845550699535f;
  constexpr float O0 = -0.02384946501937986f;
  constexpr float O1 =  0.3774028556126536f;
  constexpr float O2 =  0.3774028556126537f;
  constexpr float O3 = -0.02384946501937986f;

  const int tid = threadIdx.x;
  const int r0  = blockIdx.x * RP;
  const int b   = blockIdx.y;
  const float* inb  = in  + (size_t)b * H * W;
  float*       outb = out + (size_t)b * (2 * H) * (2 * W);

  const int c = 2 * tid;              // this thread's input cols: c, c+1
  const bool lv = (c >= 2);
  const bool rv = (c <= W - 4);

  auto loadrow = [&](int gr, f32x2& L, f32x2& M, f32x2& R) {
    const bool rowv = ((unsigned)gr < (unsigned)H);
    const float* rowp = inb + (size_t)gr * W;
    const f32x2 z = {0.0f, 0.0f};
    L = (rowv && lv) ? *reinterpret_cast<const f32x2*>(rowp + c - 2) : z;
    M =  rowv        ? *reinterpret_cast<const f32x2*>(rowp + c)     : z;
    R = (rowv && rv) ? *reinterpret_cast<const f32x2*>(rowp + c + 2) : z;
  };
  auto hfilt = [&](f32x2 L, f32x2 M, f32x2 R,
                   float& a, float& bb, float& cc, float& dd) {
    const float v0 = L.x, v1 = L.y, v2 = M.x, v3 = M.y, v4 = R.x, v5 = R.y;
    a  = v0*E0 + v1*E1 + v2*E2 + v3*E3 + v4*E4;   // he(c)   -> out col 2c
    bb = v1*O0 + v2*O1 + v3*O2 + v4*O3;           // ho(c)   -> out col 2c+1
    cc = v1*E0 + v2*E1 + v3*E2 + v4*E3 + v5*E4;   // he(c+1) -> out col 2c+2
    dd = v2*O0 + v3*O1 + v4*O2 + v5*O3;           // ho(c+1) -> out col 2c+3
  };

  // 8-slot ring: at iter t, slot k holds h-filtered row r0+4t-2+k.
  float A[8], B[8], C[8], D[8];

  // FIFOs: 4 rows being consumed this iter + 4 rows in flight for next.
  f32x2 Lf[PR], Mf[PR], Rf[PR];
  f32x2 Lg[PR], Mg[PR], Rg[PR];

  // Prologue: 8 rows of loads back-to-back (4 ring + 4 FIFO).
  f32x2 La, Ma, Ra, Lb, Mb, Rb, Lc, Mc, Rc, Ld, Md, Rd;
  loadrow(r0 - 2, La, Ma, Ra);
  loadrow(r0 - 1, Lb, Mb, Rb);
  loadrow(r0    , Lc, Mc, Rc);
  loadrow(r0 + 1, Ld, Md, Rd);
#pragma unroll
  for (int i = 0; i < PR; ++i) loadrow(r0 + 2 + i, Lf[i], Mf[i], Rf[i]);
  hfilt(La, Ma, Ra, A[0], B[0], C[0], D[0]);
  hfilt(Lb, Mb, Rb, A[1], B[1], C[1], D[1]);
  hfilt(Lc, Mc, Rc, A[2], B[2], C[2], D[2]);
  hfilt(Ld, Md, Rd, A[3], B[3], C[3], D[3]);

#pragma unroll
  for (int t = 0; t < IT; ++t) {
    if (t + 1 < IT) {                 // prefetch next iteration's 4 rows
#pragma unroll
      for (int i = 0; i < PR; ++i) loadrow(r0 + 2 + PR + i, Lg[i], Mg[i], Rg[i]);
    }

#pragma unroll
    for (int i = 0; i < PR; ++i)
      hfilt(Lf[i], Mf[i], Rf[i], A[4 + i], B[4 + i], C[4 + i], D[4 + i]);

    // 4 output row-pairs; 8 NT stores issued back-to-back.
    f32x4 ev[PR], od[PR];
#pragma unroll
    for (int i = 0; i < PR; ++i) {
      ev[i].x = A[i]*E0 + A[i+1]*E1 + A[i+2]*E2 + A[i+3]*E3 + A[i+4]*E4;
      ev[i].y = B[i]*E0 + B[i+1]*E1 + B[i+2]*E2 + B[i+3]*E3 + B[i+4]*E4;
      ev[i].z = C[i]*E0 + C[i+1]*E1 + C[i+2]*E2 + C[i+3]*E3 + C[i+4]*E4;
      ev[i].w = D[i]*E0 + D[i+1]*E1 + D[i+2]*E2 + D[i+3]*E3 + D[i+4]*E4;
      od[i].x = A[i+1]*O0 + A[i+2]*O1 + A[i+3]*O2 + A[i+4]*O3;
      od[i].y = B[i+1]*O0 + B[i+2]*O1 + B[i+3]*O2 + B[i+4]*O3;
      od[i].z = C[i+1]*O0 + C[i+2]*O1 + C[i+3]*O2 + C[i+4]*O3;
      od[i].w = D[i+1]*O0 + D[i+2]*O1 + D[i+3]*O2 + D[i+4]*O3;
    }
    const int row_e = 2 * (r0 + PR * t);
    float* base = &outb[(size_t)row_e * (2 * W) + 4 * tid];
#pragma unroll
    for (int i = 0; i < PR; ++i) {
      __builtin_nontemporal_store(ev[i], reinterpret_cast<f32x4*>(base + (size_t)(2*i)   * (2*W)));
      __builtin_nontemporal_store(od[i], reinterpret_cast<f32x4*>(base + (size_t)(2*i+1) * (2*W)));
    }

#pragma unroll
    for (int k = 0; k < 4; ++k) {
      A[k] = A[k + PR]; B[k] = B[k + PR]; C[k] = C[k + PR]; D[k] = D[k + PR];
    }
#pragma unroll
    for (int i = 0; i < PR; ++i) {
      Lf[i] = Lg[i]; Mf[i] = Mg[i]; Rf[i] = Rg[i];
    }
  }
}

extern "C" void kernel_launch(void* const* d_in, const int* in_sizes, int n_in,
                              void* d_out, int out_size, void* d_ws, size_t ws_size,
                              hipStream_t stream) {
  const float* in = (const float*)d_in[0];
  float* out = (float*)d_out;
  const int batch = in_sizes[0] / (H * W);
  dim3 grid(H / RP, batch);   // 64 x 16 = 1024 blocks -> 4 blocks/CU
  bior_up_kernel<<<grid, 256, 0, stream>>>(in, out);
}